// Round 1
// baseline (141.633 us; speedup 1.0000x reference)
//
#include <hip/hip_runtime.h>
#include <stdint.h>

// Simple exponential smoothing: level_t = (1-a)*level_{t-1} + a*y_t,
// level_0 = y_0 pinned via global initial carry s_{-1} = y_0.
// out[t] = level_t for t in [0, n-2].
//
// R9: adaptive WINDOWED-CARRY single-effective-pass.
//   The recurrence forgets at rate (1-a)^W. If (1-a)^4096 < 1e-8 (true for
//   alpha > ~4.5e-3; truncation error <= 1e-8 * |level| ~ 6e-8, vs absmax
//   margin ~2.3e-5), each block computes its OWN carry from a 4096-element
//   halo read -- no aggregates, no pass-1 full read, no grid sync.
//   k_block_agg early-exits on-device in this regime (~2-3us empty dispatch);
//   k_emit_fused branches. Exact 2-pass (R5/R8) path kept as fallback for
//   tiny alpha -- correct for ALL alpha.
//   XCD swizzle (bijective, G%8==0): consecutive tiles on the same XCD so
//   block i's halo (= tail of tile i-1) hits local L2, not HBM.
// Bans (measured): in-kernel grid sync (R2 lookback ~80us, R7 flat barrier
// ~125us — cross-XCD coherence), coop launch (R4: graph-capture reject).
//
// Affine pairs (a,b): s_out = a*s_in + b.
// combine(earlier=(a1,b1), later=(a2,b2)) = (a1*a2, a2*b1 + b2).

#define BLOCK 256
#define SEG   64                  // elements per thread
#define VPT   (SEG / 4)           // float4 per thread
#define CHUNK (BLOCK * SEG)       // 16384 elements per block
#define ROWS  65                  // padded LDS row stride -> max 2-way bank alias
#define HALO  4096                // windowed-carry history length
#define HSEG  (HALO / BLOCK)      // 16 halo elements per thread
#define HVPT  (HSEG / 4)          // 4 float4 per thread for halo
#define DECAY_THR 1e-8f           // fast path iff (1-a)^HALO < this

typedef float f32x4 __attribute__((ext_vector_type(4)));

__device__ __forceinline__ void nt_store4(float* p, float x, float y, float z, float w) {
    f32x4 v = {x, y, z, w};
    __builtin_nontemporal_store(v, (f32x4*)p);
}

// x^(2^k) via repeated squaring
__device__ __forceinline__ float pow2k(float x, int k) {
    float p = x;
#pragma unroll
    for (int i = 0; i < k; ++i) p *= p;
    return p;
}

// Inclusive Hillis-Steele scan over BLOCK affine pairs in LDS.
__device__ __forceinline__ void block_scan_affine(float* sa, float* sb, int t) {
#pragma unroll
    for (int off = 1; off < BLOCK; off <<= 1) {
        float pa = 1.0f, pb = 0.0f;
        if (t >= off) { pa = sa[t - off]; pb = sb[t - off]; }
        __syncthreads();
        if (t >= off) {
            float ca = sa[t], cb = sb[t];
            sa[t] = pa * ca;
            sb[t] = fmaf(ca, pb, cb);
        }
        __syncthreads();
    }
}

// Pass 1: per-block affine aggregate. Early-exits when the windowed-carry
// fast path applies (aggregates would never be read).
__global__ __launch_bounds__(BLOCK) void k_block_agg(
    const float* __restrict__ y, const float* __restrict__ alpha_p,
    float* __restrict__ aggA, float* __restrict__ aggB, long n)
{
    const float alpha = alpha_p[0];
    const float oma = 1.0f - alpha;
    if (pow2k(oma, 12) < DECAY_THR) return;   // fast path: skip pass 1 entirely

    const int t = threadIdx.x;
    const long base = (long)blockIdx.x * CHUNK + (long)t * SEG;

    float a = 1.0f, s = 0.0f;
    if (base + SEG <= n) {
        const float4* p = (const float4*)(y + base);
#pragma unroll
        for (int v = 0; v < VPT; ++v) {
            float4 q = p[v];
            s = fmaf(oma, s, alpha * q.x);
            s = fmaf(oma, s, alpha * q.y);
            s = fmaf(oma, s, alpha * q.z);
            s = fmaf(oma, s, alpha * q.w);
        }
        a = pow2k(oma, 6);
    } else {
        for (int k = 0; k < SEG; ++k) {
            long idx = base + k;
            if (idx < n) { s = fmaf(oma, s, alpha * y[idx]); a *= oma; }
        }
    }

    __shared__ float sa[BLOCK], sb[BLOCK];
    sa[t] = a; sb[t] = s;
    __syncthreads();
    block_scan_affine(sa, sb, t);
    if (t == BLOCK - 1) {
        aggA[blockIdx.x] = sa[t];
        aggB[blockIdx.x] = sb[t];
    }
}

// Pass 2: carry from halo window (fast) or redundant aggregate scan (slow),
// then replay from register-cached input, LDS-staged coalesced NT stores.
__global__ __launch_bounds__(BLOCK, 4) void k_emit_fused(
    const float* __restrict__ y, const float* __restrict__ alpha_p,
    const float* __restrict__ aggA, const float* __restrict__ aggB,
    float* __restrict__ out, long n, int G)
{
    __shared__ float sa[BLOCK], sb[BLOCK];
    __shared__ float stage[2 * 64 * ROWS];   // 33280 B; ~35.4 KB total -> 4 blocks/CU
    __shared__ float s_carry;

    const int t = threadIdx.x;
    // XCD-aware swizzle: consecutive tiles land on the same XCD so halo reads
    // hit the L2 lines the neighbor block just fetched. Bijective iff G%8==0.
    int tile = blockIdx.x;
    if ((G & 7) == 0) tile = (tile & 7) * (G >> 3) + (tile >> 3);

    const float alpha = alpha_p[0];
    const float oma   = 1.0f - alpha;
    const bool  fast  = (pow2k(oma, 12) < DECAY_THR);   // same fp ops as pass 1
    const long tbase = (long)tile * CHUNK;
    const long base  = tbase + (long)t * SEG;
    const bool fullTile = (tbase + CHUNK <= n);
    const float y0 = y[0];

    // ---- issue halo loads early (fast path, tile>0: halo fully in-bounds) ----
    const bool do_halo = fast && (tile > 0);
    float4 hq[HVPT];
    if (do_halo) {
        const float4* hp = (const float4*)(y + (tbase - HALO)) + t * HVPT;
#pragma unroll
        for (int v = 0; v < HVPT; ++v) hq[v] = hp[v];
    }

    // ---- phase A: load tile into registers, per-thread affine reduce ----
    float4 arr[VPT];
    float a_seg, b_seg;
    if (fullTile) {
        const float4* p = (const float4*)(y + base);
#pragma unroll
        for (int v = 0; v < VPT; ++v) arr[v] = p[v];
        float s = 0.0f;
#pragma unroll
        for (int v = 0; v < VPT; ++v) {
            s = fmaf(oma, s, alpha * arr[v].x);
            s = fmaf(oma, s, alpha * arr[v].y);
            s = fmaf(oma, s, alpha * arr[v].z);
            s = fmaf(oma, s, alpha * arr[v].w);
        }
        b_seg = s;
        a_seg = pow2k(oma, 6);
    } else {
        float a = 1.0f, s = 0.0f;
        for (int k = 0; k < SEG; ++k) {
            long idx = base + k;
            if (idx < n) { s = fmaf(oma, s, alpha * y[idx]); a *= oma; }
        }
        a_seg = a; b_seg = s;
    }

    // ---- halo reduce + block scan -> windowed carry (fast path) ----
    float carry_fast = y0;                    // exact for tile 0
    if (do_halo) {
        float hs = 0.0f;
#pragma unroll
        for (int v = 0; v < HVPT; ++v) {
            hs = fmaf(oma, hs, alpha * hq[v].x);
            hs = fmaf(oma, hs, alpha * hq[v].y);
            hs = fmaf(oma, hs, alpha * hq[v].z);
            hs = fmaf(oma, hs, alpha * hq[v].w);
        }
        sa[t] = pow2k(oma, 4);                // oma^HSEG
        sb[t] = hs;
        __syncthreads();
        block_scan_affine(sa, sb, t);
        carry_fast = sb[BLOCK - 1];           // dropped term <= 1e-8 * |level|
        __syncthreads();                      // done with sa/sb before reuse
    }

    // ---- tile scan ----
    sa[t] = a_seg; sb[t] = b_seg;
    __syncthreads();
    block_scan_affine(sa, sb, t);

    // per-thread exclusive prefix within tile (before sa/sb are reused)
    float ea_th = 1.0f, eb_th = 0.0f;
    if (t > 0) { ea_th = sa[t - 1]; eb_th = sb[t - 1]; }

    float carry;
    if (fast) {
        carry = carry_fast;
    } else {
        // ---- slow path: redundant scan of G aggregates -> this tile's carry ----
        const int items = (G + BLOCK - 1) / BLOCK;       // 4 for G=1024
        float ta = 1.0f, tb = 0.0f;
        for (int j = 0; j < items; ++j) {
            int g = t * items + j;
            if (g < G) {
                float ca = aggA[g], cb = aggB[g];
                tb = fmaf(ca, tb, cb);
                ta *= ca;
            }
        }
        __syncthreads();             // ea_th/eb_th reads done; safe to reuse sa/sb
        sa[t] = ta; sb[t] = tb;
        __syncthreads();
        block_scan_affine(sa, sb, t);

        const int q = tile / items;          // owning thread for this tile's prefix
        if (t == q) {
            float ea = (q > 0) ? sa[q - 1] : 1.0f;
            float eb = (q > 0) ? sb[q - 1] : 0.0f;
            const int r = tile - q * items;  // remaining aggregates [q*items, tile)
            for (int j = 0; j < r; ++j) {
                int g = q * items + j;
                float ca = aggA[g], cb = aggB[g];
                eb = fmaf(ca, eb, cb);
                ea *= ca;
            }
            s_carry = fmaf(ea, y0, eb);      // level just before this tile
        }
        __syncthreads();
        carry = s_carry;
    }

    float lvl = fmaf(ea_th, carry, eb_th); // level just before this thread's segment

    // ---- phase C: replay from registers, staged coalesced NT output ----
    if (fullTile) {
#pragma unroll
        for (int v = 0; v < VPT; ++v) {
            float4 q4 = arr[v], r;
            lvl = fmaf(oma, lvl, alpha * q4.x); r.x = lvl;
            lvl = fmaf(oma, lvl, alpha * q4.y); r.y = lvl;
            lvl = fmaf(oma, lvl, alpha * q4.z); r.z = lvl;
            lvl = fmaf(oma, lvl, alpha * q4.w); r.w = lvl;
            arr[v] = r;
        }
        const int  wv = t >> 6;
        const int  ln = t & 63;
        const bool lastGuard = (tbase + CHUNK > n - 1);
#pragma unroll
        for (int p = 0; p < 2; ++p) {
            __syncthreads();                       // stage reuse barrier
            if ((wv >> 1) == p) {
                int g = ((wv & 1) << 6) | ln;      // row 0..127 within phase
                float* row = &stage[g * ROWS];
#pragma unroll
                for (int v = 0; v < VPT; ++v) {
                    row[4 * v + 0] = arr[v].x;
                    row[4 * v + 1] = arr[v].y;
                    row[4 * v + 2] = arr[v].z;
                    row[4 * v + 3] = arr[v].w;
                }
            }
            __syncthreads();
            const long rbase = tbase + (long)p * 8192;
#pragma unroll
            for (int k = 0; k < 8; ++k) {
                int jj = t + (k << 8);             // float4 idx 0..2047
                int g  = jj >> 4;
                int e  = (jj << 2) & 63;
                const float* row = &stage[g * ROWS + e];
                float rx = row[0], ry = row[1], rz = row[2], rw = row[3];
                long gi = rbase + 4 * (long)jj;
                if (!lastGuard) {
                    nt_store4(out + gi, rx, ry, rz, rw);
                } else {
                    if (gi + 4 <= n - 1) {
                        nt_store4(out + gi, rx, ry, rz, rw);
                    } else {
                        if (gi + 0 < n - 1) out[gi + 0] = rx;
                        if (gi + 1 < n - 1) out[gi + 1] = ry;
                        if (gi + 2 < n - 1) out[gi + 2] = rz;
                        if (gi + 3 < n - 1) out[gi + 3] = rw;
                    }
                }
            }
        }
    } else {
        for (int k = 0; k < SEG; ++k) {
            long idx = base + k;
            if (idx < n) {
                lvl = fmaf(oma, lvl, alpha * y[idx]);
                if (idx < n - 1) out[idx] = lvl;
            }
        }
    }
}

extern "C" void kernel_launch(void* const* d_in, const int* in_sizes, int n_in,
                              void* d_out, int out_size, void* d_ws, size_t ws_size,
                              hipStream_t stream) {
    const float* y     = (const float*)d_in[0];
    const float* alpha = (const float*)d_in[1];
    float* out = (float*)d_out;
    const long n = (long)in_sizes[0];
    const int  G = (int)((n + CHUNK - 1) / CHUNK);   // 1024 for n = 2^24

    float* aggA = (float*)d_ws;        // G floats
    float* aggB = aggA + G;            // G floats (fully written before read; no zeroing)

    k_block_agg<<<G, BLOCK, 0, stream>>>(y, alpha, aggA, aggB, n);
    k_emit_fused<<<G, BLOCK, 0, stream>>>(y, alpha, aggA, aggB, out, n, G);
}